// Round 2
// baseline (744.088 us; speedup 1.0000x reference)
//
#include <hip/hip_runtime.h>

#define TT 262144
#define BB 16
#define SS 65536      // TT/4 quads per batch
#define WSTRIDE 132   // padded per-phase combined-filter length (floats)
#define QPB 1024      // output quads per block
#define TILEQ 1056    // QPB + 32 halo quads

// ---------------------------------------------------------------------------
// Kernel 0: build combined filter W[p][i] = C_p[126+p-i], i in [0,132)
//   C_p[dd] = 4 * sum_k sum_{j == 3-p mod 4} H[k][124-j-dd] * G[k][j]
//   out[4u+p] = sum_i W[p][i] * x[4u-64+i]
// ---------------------------------------------------------------------------
__global__ void build_w(const float* __restrict__ H, const float* __restrict__ G,
                        float* __restrict__ W) {
    int e = blockIdx.x * blockDim.x + threadIdx.x;
    if (e >= 4 * WSTRIDE) return;
    int p = e / WSTRIDE;
    int i = e % WSTRIDE;
    int dd = 126 + p - i;            // index into C_p, valid 0..124
    float acc = 0.f;
    if (dd >= 0 && dd <= 124) {
        int j0 = (3 - p) & 3;
        for (int k = 0; k < 4; ++k) {
            for (int j = j0; j <= 62; j += 4) {
                int a = 124 - j - dd;          // H tap index
                if (a >= 0 && a <= 62) acc += H[k * 63 + a] * G[k * 63 + j];
            }
        }
    }
    W[e] = 4.0f * acc;
}

// exact two-stage path for edge quads (s-range clamping matters there)
__device__ float4 slow_quad(const float* __restrict__ xb,
                            const float* __restrict__ H,
                            const float* __restrict__ G, int u) {
    int t0 = 4 * u;
    float acc[4] = {0.f, 0.f, 0.f, 0.f};
    int sminq = (t0 - 28) >> 2;            // ceil((t0-31)/4)
    if (sminq < 0) sminq = 0;
    int smaxq = (t0 + 34) >> 2;            // floor((t0+3+31)/4)
    if (smaxq > SS - 1) smaxq = SS - 1;

    for (int si = 0; si < 18; ++si) {
        int s = sminq + si;
        if (s > smaxq) break;
        float s0 = 0.f, s1 = 0.f, s2 = 0.f, s3 = 0.f;
        int xbase = 4 * s - 31;
        for (int a = 0; a < 63; ++a) {
            int xi = xbase + a;
            float xv = (xi >= 0 && xi < TT) ? xb[xi] : 0.f;
            s0 += xv * H[0 * 63 + a];
            s1 += xv * H[1 * 63 + a];
            s2 += xv * H[2 * 63 + a];
            s3 += xv * H[3 * 63 + a];
        }
#pragma unroll
        for (int p = 0; p < 4; ++p) {
            int j = 4 * s + 31 - (t0 + p);
            if (j >= 0 && j <= 62) {
                acc[p] += s0 * G[0 * 63 + j] + s1 * G[1 * 63 + j] +
                          s2 * G[2 * 63 + j] + s3 * G[3 * 63 + j];
            }
        }
    }
    return make_float4(4.f * acc[0], 4.f * acc[1], 4.f * acc[2], 4.f * acc[3]);
}

// ---------------------------------------------------------------------------
// Kernel 1: fused PQMF, LDS-staged. 256 threads, 4 quads/thread (interleaved
// by 64 so per-wave ds_read_b128 is contiguous). Inner loop: 8 ds : 64 fmac.
// ---------------------------------------------------------------------------
__global__ __launch_bounds__(256, 4) void pqmf_fused(const float* __restrict__ x,
                                                     const float* __restrict__ W,
                                                     const float* __restrict__ H,
                                                     const float* __restrict__ G,
                                                     float* __restrict__ out) {
    __shared__ float4 xs4[TILEQ];
    __shared__ float4 ws4[4 * 33];

    const int tid = threadIdx.x;
    const int b = blockIdx.y;
    const int Q0 = blockIdx.x * QPB;
    const float* xb = x + (size_t)b * TT;
    const float4* X4 = reinterpret_cast<const float4*>(xb);

    // ---- stage x tile (zero-fill halo outside [0,SS)) and W ----
    for (int j = tid; j < TILEQ; j += 256) {
        int gq = Q0 - 16 + j;
        xs4[j] = (gq >= 0 && gq < SS) ? X4[gq] : make_float4(0.f, 0.f, 0.f, 0.f);
    }
    if (tid < 132) ws4[tid] = reinterpret_cast<const float4*>(W)[tid];
    __syncthreads();

    const int w = tid >> 6, l = tid & 63;
    const int base = w * 256 + l;          // tile quad offset of r=0 stream

    float4 a0 = make_float4(0.f, 0.f, 0.f, 0.f);
    float4 a1 = a0, a2 = a0, a3 = a0;

#define ACCUM(ar, xv)                                                          \
    ar.x = fmaf(w0.w, xv.w, fmaf(w0.z, xv.z, fmaf(w0.y, xv.y, fmaf(w0.x, xv.x, ar.x)))); \
    ar.y = fmaf(w1.w, xv.w, fmaf(w1.z, xv.z, fmaf(w1.y, xv.y, fmaf(w1.x, xv.x, ar.y)))); \
    ar.z = fmaf(w2.w, xv.w, fmaf(w2.z, xv.z, fmaf(w2.y, xv.y, fmaf(w2.x, xv.x, ar.z)))); \
    ar.w = fmaf(w3.w, xv.w, fmaf(w3.z, xv.z, fmaf(w3.y, xv.y, fmaf(w3.x, xv.x, ar.w))));

#pragma unroll
    for (int c = 0; c < 33; ++c) {
        float4 w0 = ws4[c];
        float4 w1 = ws4[33 + c];
        float4 w2 = ws4[66 + c];
        float4 w3 = ws4[99 + c];
        float4 xv0 = xs4[base + c];
        float4 xv1 = xs4[base + 64 + c];
        float4 xv2 = xs4[base + 128 + c];
        float4 xv3 = xs4[base + 192 + c];
        ACCUM(a0, xv0)
        ACCUM(a1, xv1)
        ACCUM(a2, xv2)
        ACCUM(a3, xv3)
    }
#undef ACCUM

    float4* ob4 = reinterpret_cast<float4*>(out + (size_t)b * TT);
    const int u0 = Q0 + base;
    float4 res[4] = {a0, a1, a2, a3};
#pragma unroll
    for (int r = 0; r < 4; ++r) {
        int u = u0 + r * 64;
        float4 v = res[r];
        if (u < 16 || u >= SS - 16) v = slow_quad(xb, H, G, u);   // exact edges
        ob4[u] = v;
    }
}

extern "C" void kernel_launch(void* const* d_in, const int* in_sizes, int n_in,
                              void* d_out, int out_size, void* d_ws, size_t ws_size,
                              hipStream_t stream) {
    const float* x = (const float*)d_in[0];
    const float* H = (const float*)d_in[1];
    const float* G = (const float*)d_in[2];
    float* outp = (float*)d_out;
    float* W = (float*)d_ws;   // 4*132 floats = 2112 B

    hipLaunchKernelGGL(build_w, dim3(3), dim3(256), 0, stream, H, G, W);
    hipLaunchKernelGGL(pqmf_fused, dim3(SS / QPB, BB), dim3(256), 0, stream,
                       x, W, H, G, outp);
}

// Round 8
// 89.180 us; speedup vs baseline: 8.3437x; 8.3437x over previous
//
#include <hip/hip_runtime.h>

#define TT 262144
#define BB 16
#define SS 65536      // TT/4 quads per batch
#define WSTRIDE 132   // padded per-phase combined-filter length (floats)
#define QPB 512       // output quads per block
#define TILEQ 544     // QPB + 32 halo quads

// exact two-stage path for edge quads (s-range clamping matters there)
__device__ __forceinline__ float4 slow_quad(const float* __restrict__ xb,
                                            const float* __restrict__ H,
                                            const float* __restrict__ G, int u) {
    int t0 = 4 * u;
    float acc[4] = {0.f, 0.f, 0.f, 0.f};
    int sminq = (t0 - 28) >> 2;            // ceil((t0-31)/4)
    if (sminq < 0) sminq = 0;
    int smaxq = (t0 + 34) >> 2;            // floor((t0+3+31)/4)
    if (smaxq > SS - 1) smaxq = SS - 1;

    for (int si = 0; si < 18; ++si) {
        int s = sminq + si;
        if (s > smaxq) break;
        float s0 = 0.f, s1 = 0.f, s2 = 0.f, s3 = 0.f;
        int xbase = 4 * s - 31;
        for (int a = 0; a < 63; ++a) {
            int xi = xbase + a;
            float xv = (xi >= 0 && xi < TT) ? xb[xi] : 0.f;
            s0 += xv * H[0 * 63 + a];
            s1 += xv * H[1 * 63 + a];
            s2 += xv * H[2 * 63 + a];
            s3 += xv * H[3 * 63 + a];
        }
#pragma unroll
        for (int p = 0; p < 4; ++p) {
            int j = 4 * s + 31 - (t0 + p);
            if (j >= 0 && j <= 62) {
                acc[p] += s0 * G[0 * 63 + j] + s1 * G[1 * 63 + j] +
                          s2 * G[2 * 63 + j] + s3 * G[3 * 63 + j];
            }
        }
    }
    return make_float4(4.f * acc[0], 4.f * acc[1], 4.f * acc[2], 4.f * acc[3]);
}

// ---------------------------------------------------------------------------
// Kernel 0 (prep): blocks 0-2 build combined filter W; blocks 3-4 compute the
// 512 edge quads (u<16 or u>=SS-16, all batches) via the exact slow path.
// Main kernel skips those stores, so writes are disjoint.
// ---------------------------------------------------------------------------
__global__ __launch_bounds__(256) void prep(const float* __restrict__ x,
                                            const float* __restrict__ H,
                                            const float* __restrict__ G,
                                            float* __restrict__ W,
                                            float* __restrict__ out) {
    int blk = blockIdx.x;
    int tid = threadIdx.x;
    if (blk < 3) {
        int e = blk * 256 + tid;
        if (e >= 4 * WSTRIDE) return;
        int p = e / WSTRIDE;
        int i = e % WSTRIDE;
        int dd = 126 + p - i;            // index into C_p, valid 0..124
        float acc = 0.f;
        if (dd >= 0 && dd <= 124) {
            int j0 = (3 - p) & 3;
            for (int k = 0; k < 4; ++k) {
                for (int j = j0; j <= 62; j += 4) {
                    int a = 124 - j - dd;          // H tap index
                    if (a >= 0 && a <= 62) acc += H[k * 63 + a] * G[k * 63 + j];
                }
            }
        }
        W[e] = 4.0f * acc;
    } else {
        int e = (blk - 3) * 256 + tid;   // 0..511
        if (e >= 512) return;
        int b = e >> 5;                  // batch
        int idx = e & 31;
        int u = (idx < 16) ? idx : (SS - 32 + idx);
        const float* xb = x + (size_t)b * TT;
        float4 v = slow_quad(xb, H, G, u);
        reinterpret_cast<float4*>(out + (size_t)b * TT)[u] = v;
    }
}

// ---------------------------------------------------------------------------
// Kernel 1: fused PQMF, LDS-staged. 256 threads, 2 quads/thread (interleaved
// by 64 lanes). Inner loop: 6 ds_read_b128 (4 uniform) : 32 fmac.
// Phase mapping (validated in round 2): out component p <- W[p] = ws4[33p+c].
// ---------------------------------------------------------------------------
__global__ __launch_bounds__(256) void pqmf_fused(const float* __restrict__ x,
                                                  const float* __restrict__ W,
                                                  float* __restrict__ out) {
    __shared__ float4 xs4[TILEQ];
    __shared__ float4 ws4[132];

    const int tid = threadIdx.x;
    const int b = blockIdx.y;
    const int Q0 = blockIdx.x * QPB;
    const float4* X4 = reinterpret_cast<const float4*>(x + (size_t)b * TT);

    // ---- stage x tile (zero-fill halo outside [0,SS)) and W ----
    const int gq0 = Q0 - 16;
    for (int j = tid; j < TILEQ; j += 256) {
        int gq = gq0 + j;
        xs4[j] = (gq >= 0 && gq < SS) ? X4[gq] : make_float4(0.f, 0.f, 0.f, 0.f);
    }
    if (tid < 132) ws4[tid] = reinterpret_cast<const float4*>(W)[tid];
    __syncthreads();

    const int w = tid >> 6, l = tid & 63;
    const int q0 = w * 128 + l;          // block-local quad of stream 0

    float4 a0 = make_float4(0.f, 0.f, 0.f, 0.f);
    float4 a1 = make_float4(0.f, 0.f, 0.f, 0.f);

#define ACCUM(ar, xv)                                                          \
    ar.x = fmaf(W0.w, xv.w, fmaf(W0.z, xv.z, fmaf(W0.y, xv.y, fmaf(W0.x, xv.x, ar.x)))); \
    ar.y = fmaf(W1.w, xv.w, fmaf(W1.z, xv.z, fmaf(W1.y, xv.y, fmaf(W1.x, xv.x, ar.y)))); \
    ar.z = fmaf(W2.w, xv.w, fmaf(W2.z, xv.z, fmaf(W2.y, xv.y, fmaf(W2.x, xv.x, ar.z)))); \
    ar.w = fmaf(W3.w, xv.w, fmaf(W3.z, xv.z, fmaf(W3.y, xv.y, fmaf(W3.x, xv.x, ar.w))));

#pragma unroll 3
    for (int c = 0; c < 33; ++c) {
        float4 W0 = ws4[c];              // phase 0 -> .x
        float4 W1 = ws4[33 + c];         // phase 1 -> .y
        float4 W2 = ws4[66 + c];         // phase 2 -> .z
        float4 W3 = ws4[99 + c];         // phase 3 -> .w
        float4 xv0 = xs4[q0 + c];
        float4 xv1 = xs4[q0 + 64 + c];
        ACCUM(a0, xv0)
        ACCUM(a1, xv1)
    }
#undef ACCUM

    float4* ob4 = reinterpret_cast<float4*>(out + (size_t)b * TT);
    const int u0 = Q0 + q0;
    if ((unsigned)(u0 - 16) < (unsigned)(SS - 32)) ob4[u0] = a0;
    const int u1 = u0 + 64;
    if ((unsigned)(u1 - 16) < (unsigned)(SS - 32)) ob4[u1] = a1;
}

extern "C" void kernel_launch(void* const* d_in, const int* in_sizes, int n_in,
                              void* d_out, int out_size, void* d_ws, size_t ws_size,
                              hipStream_t stream) {
    const float* x = (const float*)d_in[0];
    const float* H = (const float*)d_in[1];
    const float* G = (const float*)d_in[2];
    float* outp = (float*)d_out;
    float* W = (float*)d_ws;   // 4*132 floats = 2112 B

    hipLaunchKernelGGL(prep, dim3(5), dim3(256), 0, stream, x, H, G, W, outp);
    hipLaunchKernelGGL(pqmf_fused, dim3(SS / QPB, BB), dim3(256), 0, stream,
                       x, W, outp);
}

// Round 9
// 32.962 us; speedup vs baseline: 22.5739x; 2.7055x over previous
//
#include <hip/hip_runtime.h>

#define TT 262144
#define BB 16
#define SS 65536      // TT/4 quads per batch
#define WSTRIDE 132   // padded per-phase combined-filter length (floats)
#define QPB 1024      // output quads per block
#define TILEQ 1056    // QPB + 32 halo quads

// ---------------------------------------------------------------------------
// prep: blocks 0..31  -> edge quads, one thread per (quad, s-slot).
//       blocks 32..34 -> build combined filter W.
// Edge math: out[4u+p] needs s in [max(0,u-7), min(SS-1,u+8)] (<=16 values).
// Thread (q_local, s_idx): s = u-7+s_idx; contributions reduced over the
// 16-lane s-group via shfl_xor. Writes exactly the quads the main kernel
// skips (u<16 or u>=SS-16), so stores are disjoint.
// ---------------------------------------------------------------------------
__global__ __launch_bounds__(256) void prep(const float* __restrict__ x,
                                            const float* __restrict__ H,
                                            const float* __restrict__ G,
                                            float* __restrict__ W,
                                            float* __restrict__ out) {
    const int blk = blockIdx.x;
    const int tid = threadIdx.x;

    if (blk >= 32) {
        // ---- W build (validated in rounds 2/8) ----
        int e = (blk - 32) * 256 + tid;
        if (e >= 4 * WSTRIDE) return;
        int p = e / WSTRIDE;
        int i = e % WSTRIDE;
        int dd = 126 + p - i;            // index into C_p, valid 0..124
        float acc = 0.f;
        if (dd >= 0 && dd <= 124) {
            int j0 = (3 - p) & 3;
            for (int k = 0; k < 4; ++k) {
                for (int j = j0; j <= 62; j += 4) {
                    int a = 124 - j - dd;          // H tap index
                    if (a >= 0 && a <= 62) acc += H[k * 63 + a] * G[k * 63 + j];
                }
            }
        }
        W[e] = 4.0f * acc;
        return;
    }

    // ---- edge quads ----
    const int q_local = tid >> 4;        // 0..15
    const int s_idx = tid & 15;          // 0..15
    const int e = blk * 16 + q_local;    // 0..511
    const int b = e >> 5;                // batch
    const int idx = e & 31;
    const int u = (idx < 16) ? idx : (SS - 32 + idx);
    const float* xb = x + (size_t)b * TT;

    const int s = u - 7 + s_idx;         // s range clamp via validity check
    float c0 = 0.f, c1 = 0.f, c2 = 0.f, c3 = 0.f;
    if (s >= 0 && s < SS) {
        float s0 = 0.f, s1 = 0.f, s2 = 0.f, s3 = 0.f;
        const int xbase = 4 * s - 31;
#pragma unroll
        for (int a = 0; a < 63; ++a) {
            int xi = xbase + a;
            float xv = (xi >= 0 && xi < TT) ? xb[xi] : 0.f;
            s0 += xv * H[a];
            s1 += xv * H[63 + a];
            s2 += xv * H[126 + a];
            s3 += xv * H[189 + a];
        }
        const int d4 = 4 * (s - u);      // -28..32
        {
            int j = d4 + 31;             // p = 0
            if (j <= 62) c0 = s0 * G[j] + s1 * G[63 + j] + s2 * G[126 + j] + s3 * G[189 + j];
        }
        {
            int j = d4 + 30;             // p = 1
            c1 = s0 * G[j] + s1 * G[63 + j] + s2 * G[126 + j] + s3 * G[189 + j];
        }
        {
            int j = d4 + 29;             // p = 2
            c2 = s0 * G[j] + s1 * G[63 + j] + s2 * G[126 + j] + s3 * G[189 + j];
        }
        {
            int j = d4 + 28;             // p = 3
            c3 = s0 * G[j] + s1 * G[63 + j] + s2 * G[126 + j] + s3 * G[189 + j];
        }
    }
    // reduce over the 16 s-slots (masks <16 stay within the 16-lane group)
#pragma unroll
    for (int m = 8; m >= 1; m >>= 1) {
        c0 += __shfl_xor(c0, m);
        c1 += __shfl_xor(c1, m);
        c2 += __shfl_xor(c2, m);
        c3 += __shfl_xor(c3, m);
    }
    if (s_idx == 0) {
        float4 v = make_float4(4.f * c0, 4.f * c1, 4.f * c2, 4.f * c3);
        reinterpret_cast<float4*>(out + (size_t)b * TT)[u] = v;
    }
}

// ---------------------------------------------------------------------------
// Main kernel: fused PQMF, LDS-staged, 4 quads/thread (strided by 64 lanes).
// Per c-iter: 8 ds_read_b128 (4 wave-uniform broadcasts) : 64 fmac.
// Phase mapping (validated round 2/8): out component p <- ws4[33p + c].
// ---------------------------------------------------------------------------
__global__ __launch_bounds__(256) void pqmf_fused(const float* __restrict__ x,
                                                  const float* __restrict__ W,
                                                  float* __restrict__ out) {
    __shared__ float4 xs4[TILEQ];
    __shared__ float4 ws4[132];

    const int tid = threadIdx.x;
    const int b = blockIdx.y;
    const int Q0 = blockIdx.x * QPB;
    const float4* X4 = reinterpret_cast<const float4*>(x + (size_t)b * TT);

    // ---- stage x tile (zero-fill halo outside [0,SS)) and W ----
    const int gq0 = Q0 - 16;
    for (int j = tid; j < TILEQ; j += 256) {
        int gq = gq0 + j;
        xs4[j] = (gq >= 0 && gq < SS) ? X4[gq] : make_float4(0.f, 0.f, 0.f, 0.f);
    }
    if (tid < 132) ws4[tid] = reinterpret_cast<const float4*>(W)[tid];
    __syncthreads();

    const int w = tid >> 6, l = tid & 63;
    const int base = w * 256 + l;        // block-local quad of stream 0

    float4 a0 = make_float4(0.f, 0.f, 0.f, 0.f);
    float4 a1 = a0, a2 = a0, a3 = a0;

#define ACCUM(ar, xv)                                                          \
    ar.x = fmaf(W0.w, xv.w, fmaf(W0.z, xv.z, fmaf(W0.y, xv.y, fmaf(W0.x, xv.x, ar.x)))); \
    ar.y = fmaf(W1.w, xv.w, fmaf(W1.z, xv.z, fmaf(W1.y, xv.y, fmaf(W1.x, xv.x, ar.y)))); \
    ar.z = fmaf(W2.w, xv.w, fmaf(W2.z, xv.z, fmaf(W2.y, xv.y, fmaf(W2.x, xv.x, ar.z)))); \
    ar.w = fmaf(W3.w, xv.w, fmaf(W3.z, xv.z, fmaf(W3.y, xv.y, fmaf(W3.x, xv.x, ar.w))));

#pragma unroll 2
    for (int c = 0; c < 33; ++c) {
        float4 W0 = ws4[c];              // phase 0 -> .x
        float4 W1 = ws4[33 + c];         // phase 1 -> .y
        float4 W2 = ws4[66 + c];         // phase 2 -> .z
        float4 W3 = ws4[99 + c];         // phase 3 -> .w
        float4 xv0 = xs4[base + c];
        float4 xv1 = xs4[base + 64 + c];
        float4 xv2 = xs4[base + 128 + c];
        float4 xv3 = xs4[base + 192 + c];
        ACCUM(a0, xv0)
        ACCUM(a1, xv1)
        ACCUM(a2, xv2)
        ACCUM(a3, xv3)
    }
#undef ACCUM

    float4* ob4 = reinterpret_cast<float4*>(out + (size_t)b * TT);
    const int u0 = Q0 + base;
    if ((unsigned)(u0 - 16) < (unsigned)(SS - 32)) ob4[u0] = a0;
    if ((unsigned)(u0 + 64 - 16) < (unsigned)(SS - 32)) ob4[u0 + 64] = a1;
    if ((unsigned)(u0 + 128 - 16) < (unsigned)(SS - 32)) ob4[u0 + 128] = a2;
    if ((unsigned)(u0 + 192 - 16) < (unsigned)(SS - 32)) ob4[u0 + 192] = a3;
}

extern "C" void kernel_launch(void* const* d_in, const int* in_sizes, int n_in,
                              void* d_out, int out_size, void* d_ws, size_t ws_size,
                              hipStream_t stream) {
    const float* x = (const float*)d_in[0];
    const float* H = (const float*)d_in[1];
    const float* G = (const float*)d_in[2];
    float* outp = (float*)d_out;
    float* W = (float*)d_ws;   // 4*132 floats = 2112 B

    hipLaunchKernelGGL(prep, dim3(35), dim3(256), 0, stream, x, H, G, W, outp);
    hipLaunchKernelGGL(pqmf_fused, dim3(SS / QPB, BB), dim3(256), 0, stream,
                       x, W, outp);
}

// Round 10
// 27.278 us; speedup vs baseline: 27.2775x; 1.2084x over previous
//
#include <hip/hip_runtime.h>

#define TT 262144
#define BB 16
#define SS 65536      // TT/4 quads per batch
#define QPB 1024      // output quads per block
#define TILEQ 1056    // QPB + 32 halo quads

// ---------------------------------------------------------------------------
// prep_w: build combined filter W only. One thread per (entry e, band k);
// 4-lane shfl reduce over k. W[p*132+i] with
//   out[4u+p] = sum_i W[p][i] * x[4u-64+i],
//   W[p][i]   = 4 * C_p[126+p-i],
//   C_p[dd]   = sum_k sum_{j==3-p (4)} H[k][124-j-dd] * G[k][j]
// ---------------------------------------------------------------------------
__global__ __launch_bounds__(256) void prep_w(const float* __restrict__ H,
                                              const float* __restrict__ G,
                                              float* __restrict__ W) {
    int t = blockIdx.x * 256 + threadIdx.x;   // 0..2303
    int e = t >> 2;
    int k = t & 3;
    bool valid = (e < 4 * 132);
    float acc = 0.f;
    if (valid) {
        int p = e / 132;
        int i = e % 132;
        int dd = 126 + p - i;                 // valid 0..124
        if (dd >= 0 && dd <= 124) {
            int j0 = (3 - p) & 3;
#pragma unroll
            for (int jj = 0; jj < 16; ++jj) {
                int j = j0 + 4 * jj;
                if (j <= 62) {
                    int a = 124 - j - dd;
                    if (a >= 0 && a <= 62) acc += H[k * 63 + a] * G[k * 63 + j];
                }
            }
        }
    }
    acc += __shfl_xor(acc, 1);
    acc += __shfl_xor(acc, 2);
    if (valid && k == 0) W[e] = 4.0f * acc;
}

// ---------------------------------------------------------------------------
// Fused PQMF. x tile staged in LDS (zero-padded halo); W read from GLOBAL
// with uniform indices -> scalar s_load path (frees the LDS pipe).
// 4 quads/thread strided by 64 lanes. Blocks 0 / gridDim.x-1 additionally
// compute the 16 edge quads each via the exact two-stage path (parallel
// over 16 s-slots), reading x from the staged LDS tile.
// Phase mapping (validated rounds 2/8/9): out component p <- W4[33p + c].
// ---------------------------------------------------------------------------
__global__ __launch_bounds__(256) void pqmf_fused(const float* __restrict__ x,
                                                  const float* __restrict__ Wg,
                                                  const float* __restrict__ H,
                                                  const float* __restrict__ G,
                                                  float* __restrict__ out) {
    __shared__ float4 xs4[TILEQ];

    const int tid = threadIdx.x;
    const int b = blockIdx.y;
    const int Q0 = blockIdx.x * QPB;
    const float4* X4 = reinterpret_cast<const float4*>(x + (size_t)b * TT);

    // ---- stage x tile (zero-fill halo outside [0,SS)) ----
    const int gq0 = Q0 - 16;
    for (int j = tid; j < TILEQ; j += 256) {
        int gq = gq0 + j;
        xs4[j] = (gq >= 0 && gq < SS) ? X4[gq] : make_float4(0.f, 0.f, 0.f, 0.f);
    }
    __syncthreads();

    const int w = tid >> 6, l = tid & 63;
    const int base = w * 256 + l;        // block-local quad of stream 0

    float4 a0 = make_float4(0.f, 0.f, 0.f, 0.f);
    float4 a1 = a0, a2 = a0, a3 = a0;

    const float4* W4 = reinterpret_cast<const float4*>(Wg);

#define ACCUM(ar, xv)                                                          \
    ar.x = fmaf(W0.w, xv.w, fmaf(W0.z, xv.z, fmaf(W0.y, xv.y, fmaf(W0.x, xv.x, ar.x)))); \
    ar.y = fmaf(W1.w, xv.w, fmaf(W1.z, xv.z, fmaf(W1.y, xv.y, fmaf(W1.x, xv.x, ar.y)))); \
    ar.z = fmaf(W2.w, xv.w, fmaf(W2.z, xv.z, fmaf(W2.y, xv.y, fmaf(W2.x, xv.x, ar.z)))); \
    ar.w = fmaf(W3.w, xv.w, fmaf(W3.z, xv.z, fmaf(W3.y, xv.y, fmaf(W3.x, xv.x, ar.w))));

#pragma unroll 3
    for (int c = 0; c < 33; ++c) {
        float4 W0 = W4[c];               // uniform -> s_load, phase 0 -> .x
        float4 W1 = W4[33 + c];          // phase 1 -> .y
        float4 W2 = W4[66 + c];          // phase 2 -> .z
        float4 W3 = W4[99 + c];          // phase 3 -> .w
        float4 xv0 = xs4[base + c];
        float4 xv1 = xs4[base + 64 + c];
        float4 xv2 = xs4[base + 128 + c];
        float4 xv3 = xs4[base + 192 + c];
        ACCUM(a0, xv0)
        ACCUM(a1, xv1)
        ACCUM(a2, xv2)
        ACCUM(a3, xv3)
    }
#undef ACCUM

    float4* ob4 = reinterpret_cast<float4*>(out + (size_t)b * TT);
    const int u0 = Q0 + base;
    if ((unsigned)(u0 - 16) < (unsigned)(SS - 32)) ob4[u0] = a0;
    if ((unsigned)(u0 + 64 - 16) < (unsigned)(SS - 32)) ob4[u0 + 64] = a1;
    if ((unsigned)(u0 + 128 - 16) < (unsigned)(SS - 32)) ob4[u0 + 128] = a2;
    if ((unsigned)(u0 + 192 - 16) < (unsigned)(SS - 32)) ob4[u0 + 192] = a3;

    // ---- edge quads (exact two-stage), only first/last block per batch ----
    const bool edgeLo = (blockIdx.x == 0);
    const bool edgeHi = (blockIdx.x == gridDim.x - 1);
    if (edgeLo || edgeHi) {
        const int q_local = tid >> 4;    // 0..15
        const int s_idx = tid & 15;      // 0..15
        const int u = edgeLo ? q_local : (SS - 16 + q_local);
        const int s = u - 7 + s_idx;
        float c0 = 0.f, c1 = 0.f, c2 = 0.f, c3 = 0.f;
        if (s >= 0 && s < SS) {
            const float* xsf = reinterpret_cast<const float*>(xs4);
            // x[xi] == xsf[xi - 4*Q0 + 64]; coverage verified for both edges
            const int lbase = 4 * s - 31 - 4 * Q0 + 64;
            float s0 = 0.f, s1 = 0.f, s2 = 0.f, s3 = 0.f;
#pragma unroll
            for (int a = 0; a < 63; ++a) {
                float xv = xsf[lbase + a];
                s0 += xv * H[a];
                s1 += xv * H[63 + a];
                s2 += xv * H[126 + a];
                s3 += xv * H[189 + a];
            }
            const int d4 = 4 * (s - u);  // -28..32
            {
                int j = d4 + 31;         // p = 0 (needs upper guard: j can be 63)
                if (j <= 62) c0 = s0 * G[j] + s1 * G[63 + j] + s2 * G[126 + j] + s3 * G[189 + j];
            }
            {
                int j = d4 + 30;         // p = 1, j in [2,62]
                c1 = s0 * G[j] + s1 * G[63 + j] + s2 * G[126 + j] + s3 * G[189 + j];
            }
            {
                int j = d4 + 29;         // p = 2, j in [1,61]
                c2 = s0 * G[j] + s1 * G[63 + j] + s2 * G[126 + j] + s3 * G[189 + j];
            }
            {
                int j = d4 + 28;         // p = 3, j in [0,60]
                c3 = s0 * G[j] + s1 * G[63 + j] + s2 * G[126 + j] + s3 * G[189 + j];
            }
        }
#pragma unroll
        for (int m = 8; m >= 1; m >>= 1) {
            c0 += __shfl_xor(c0, m);
            c1 += __shfl_xor(c1, m);
            c2 += __shfl_xor(c2, m);
            c3 += __shfl_xor(c3, m);
        }
        if (s_idx == 0) {
            float4 v = make_float4(4.f * c0, 4.f * c1, 4.f * c2, 4.f * c3);
            ob4[u] = v;
        }
    }
}

extern "C" void kernel_launch(void* const* d_in, const int* in_sizes, int n_in,
                              void* d_out, int out_size, void* d_ws, size_t ws_size,
                              hipStream_t stream) {
    const float* x = (const float*)d_in[0];
    const float* H = (const float*)d_in[1];
    const float* G = (const float*)d_in[2];
    float* outp = (float*)d_out;
    float* W = (float*)d_ws;   // 4*132 floats = 2112 B

    hipLaunchKernelGGL(prep_w, dim3(9), dim3(256), 0, stream, H, G, W);
    hipLaunchKernelGGL(pqmf_fused, dim3(SS / QPB, BB), dim3(256), 0, stream,
                       x, W, H, G, outp);
}